// Round 1
// baseline (6062.140 us; speedup 1.0000x reference)
//
#include <hip/hip_runtime.h>

// Problem dims (validated against in_sizes at launch)
// N=100000 nodes, E=1600000 edges, IN=128, H=64, R=32, B=512
constexpr int HD   = 64;   // hidden dim
constexpr int RNUM = 32;   // relations
constexpr int EPB  = 256;  // edges per block chunk (single-type guaranteed via padding)

#define WS_ALIGN(x) (((x) + size_t(255)) & ~size_t(255))

// ---------------- preprocessing ----------------

// count edges per (dst, type) and per-type histogram
__global__ __launch_bounds__(256) void count_kernel(
    const int* __restrict__ dst, const int* __restrict__ et,
    int* __restrict__ cnt, int* __restrict__ hist, int E)
{
    __shared__ int lh[RNUM];
    if (threadIdx.x < RNUM) lh[threadIdx.x] = 0;
    __syncthreads();
    int e = blockIdx.x * 256 + threadIdx.x;
    if (e < E) {
        int t = et[e];
        int d = dst[e];
        atomicAdd(&cnt[(size_t)d * RNUM + t], 1);
        atomicAdd(&lh[t], 1);
    }
    __syncthreads();
    if (threadIdx.x < RNUM && lh[threadIdx.x] > 0)
        atomicAdd(&hist[threadIdx.x], lh[threadIdx.x]);
}

// exclusive scan over 32 buckets, padding each to EPB multiple
__global__ void scan_kernel(const int* __restrict__ hist, int* __restrict__ poff)
{
    if (threadIdx.x == 0) {
        int acc = 0;
        poff[0] = 0;
        for (int r = 0; r < RNUM; ++r) {
            acc += ((hist[r] + EPB - 1) / EPB) * EPB;
            poff[r + 1] = acc;
        }
    }
}

// cnt(int) -> 1/max(cnt,1) (float) in place
__global__ __launch_bounds__(256) void invert_kernel(int* __restrict__ cnt, int total)
{
    int i = blockIdx.x * 256 + threadIdx.x;
    if (i < total) {
        int c = cnt[i];
        float v = 1.0f / (float)(c > 1 ? c : 1);
        ((float*)cnt)[i] = v;
    }
}

// counting-sort scatter: src_s/dst_s ordered by type into padded buckets
__global__ __launch_bounds__(256) void scatter_kernel(
    const int* __restrict__ src, const int* __restrict__ dst,
    const int* __restrict__ et, const int* __restrict__ poff,
    int* __restrict__ cursor, int* __restrict__ src_s, int* __restrict__ dst_s, int E)
{
    __shared__ int lh[RNUM], lbase[RNUM];
    if (threadIdx.x < RNUM) lh[threadIdx.x] = 0;
    __syncthreads();
    int e = blockIdx.x * 256 + threadIdx.x;
    int t = 0, rank = 0;
    bool valid = (e < E);
    if (valid) {
        t = et[e];
        rank = atomicAdd(&lh[t], 1);
    }
    __syncthreads();
    if (threadIdx.x < RNUM && lh[threadIdx.x] > 0)
        lbase[threadIdx.x] = atomicAdd(&cursor[threadIdx.x], lh[threadIdx.x]);
    __syncthreads();
    if (valid) {
        int pos = poff[t] + lbase[t] + rank;
        src_s[pos] = src[e];
        dst_s[pos] = dst[e];
    }
}

// ---------------- dense kernels ----------------

// out[n][j] = bias[j] + sum_k x[n][k] * Wr[k][j]
template<int K>
__global__ __launch_bounds__(256) void root_kernel(
    const float* __restrict__ x, const float* __restrict__ Wr,
    const float* __restrict__ bias, float* __restrict__ out, int n)
{
    __shared__ float sW[K * HD];
    {
        const float4* Wg = (const float4*)Wr;
        float4* s4 = (float4*)sW;
        for (int i = threadIdx.x; i < K * HD / 4; i += 256) s4[i] = Wg[i];
    }
    __syncthreads();
    const int lane = threadIdx.x & 63;
    const float b = bias[lane];
    const int base = blockIdx.x * 128 + (threadIdx.x >> 6) * 32;
    for (int g = 0; g < 32; g += 8) {
        int nb = base + g;
        if (nb >= n) return;
        const float* xp[8];
#pragma unroll
        for (int u = 0; u < 8; ++u) {
            int node = nb + u;
            if (node >= n) node = n - 1;
            xp[u] = x + (size_t)node * K;
        }
        float acc[8];
#pragma unroll
        for (int u = 0; u < 8; ++u) acc[u] = 0.f;
#pragma unroll 2
        for (int k = 0; k < K; k += 4) {
            float w0 = sW[(k + 0) * HD + lane];
            float w1 = sW[(k + 1) * HD + lane];
            float w2 = sW[(k + 2) * HD + lane];
            float w3 = sW[(k + 3) * HD + lane];
#pragma unroll
            for (int u = 0; u < 8; ++u) {
                float4 xv = *(const float4*)(xp[u] + k);
                acc[u] = fmaf(xv.x, w0, acc[u]);
                acc[u] = fmaf(xv.y, w1, acc[u]);
                acc[u] = fmaf(xv.z, w2, acc[u]);
                acc[u] = fmaf(xv.w, w3, acc[u]);
            }
        }
#pragma unroll
        for (int u = 0; u < 8; ++u) {
            int node = nb + u;
            if (node < n) out[(size_t)node * HD + lane] = acc[u] + b;
        }
    }
}

// per-edge message: out[dst][j] += inv_cnt[dst][t] * sum_k x[src][k]*W[t][k][j]
template<int K>
__global__ __launch_bounds__(256) void edge_kernel(
    const float* __restrict__ x,
    const int* __restrict__ src_s, const int* __restrict__ dst_s,
    const float* __restrict__ inv_cnt,
    const int* __restrict__ poff, const int* __restrict__ hist,
    const float* __restrict__ W, float* __restrict__ out)
{
    __shared__ float sW[K * HD];
    const int e0 = blockIdx.x * EPB;
    int t = 0;
#pragma unroll
    for (int r = 1; r <= RNUM; ++r) t += (e0 >= poff[r]) ? 1 : 0;
    if (t >= RNUM) return;
    const int vend = poff[t] + hist[t];
    if (e0 >= vend) return;

    {
        const float4* Wg = (const float4*)(W + (size_t)t * K * HD);
        float4* s4 = (float4*)sW;
        for (int i = threadIdx.x; i < K * HD / 4; i += 256) s4[i] = Wg[i];
    }
    __syncthreads();

    const int lane = threadIdx.x & 63;
    const int wbase = e0 + (threadIdx.x >> 6) * 64;

    for (int g = 0; g < 64; g += 8) {
        const int eb = wbase + g;
        if (eb >= vend) break;
        const float* xp[8];
        float sc[8];
        int dd[8];
#pragma unroll
        for (int u = 0; u < 8; ++u) {
            int e = eb + u;
            bool v = (e < vend);
            int s = src_s[v ? e : eb];
            xp[u] = x + (size_t)s * K;
            int d = v ? dst_s[e] : 0;
            dd[u] = d;
            sc[u] = v ? inv_cnt[(size_t)d * RNUM + t] : 0.f;
        }
        float acc[8];
#pragma unroll
        for (int u = 0; u < 8; ++u) acc[u] = 0.f;
#pragma unroll 2
        for (int k = 0; k < K; k += 4) {
            float w0 = sW[(k + 0) * HD + lane];
            float w1 = sW[(k + 1) * HD + lane];
            float w2 = sW[(k + 2) * HD + lane];
            float w3 = sW[(k + 3) * HD + lane];
#pragma unroll
            for (int u = 0; u < 8; ++u) {
                float4 xv = *(const float4*)(xp[u] + k);
                acc[u] = fmaf(xv.x, w0, acc[u]);
                acc[u] = fmaf(xv.y, w1, acc[u]);
                acc[u] = fmaf(xv.z, w2, acc[u]);
                acc[u] = fmaf(xv.w, w3, acc[u]);
            }
        }
#pragma unroll
        for (int u = 0; u < 8; ++u) {
            if (sc[u] > 0.f)
                unsafeAtomicAdd(&out[(size_t)dd[u] * HD + lane], acc[u] * sc[u]);
        }
    }
}

__global__ __launch_bounds__(256) void relu_kernel(float* __restrict__ h, int total4)
{
    int i = blockIdx.x * 256 + threadIdx.x;
    if (i < total4) {
        float4 v = ((float4*)h)[i];
        v.x = fmaxf(v.x, 0.f);
        v.y = fmaxf(v.y, 0.f);
        v.z = fmaxf(v.z, 0.f);
        v.w = fmaxf(v.w, 0.f);
        ((float4*)h)[i] = v;
    }
}

// mean-pool relu(h) per graph; batch is sorted, so register-accumulate runs
__global__ __launch_bounds__(256) void pool_kernel(
    const float* __restrict__ h, const int* __restrict__ batch,
    float* __restrict__ pool, float* __restrict__ gcnt, int col0, int n)
{
    const int lane = threadIdx.x & 63;
    const int wid = (blockIdx.x * 256 + threadIdx.x) >> 6;
    const int RANGE = 256;
    int n0 = wid * RANGE;
    if (n0 >= n) return;
    int n1 = n0 + RANGE;
    if (n1 > n) n1 = n;
    int cur = batch[n0];
    float acc = 0.f, c = 0.f;
    for (int i = n0; i < n1; ++i) {
        int b = batch[i];
        if (b != cur) {
            unsafeAtomicAdd(&pool[(size_t)cur * 128 + col0 + lane], acc);
            if (lane == 0) unsafeAtomicAdd(&gcnt[cur], c);
            acc = 0.f;
            c = 0.f;
            cur = b;
        }
        acc += fmaxf(h[(size_t)i * HD + lane], 0.f);
        c += 1.f;
    }
    unsafeAtomicAdd(&pool[(size_t)cur * 128 + col0 + lane], acc);
    if (lane == 0) unsafeAtomicAdd(&gcnt[cur], c);
}

__global__ __launch_bounds__(512) void depth_kernel(
    const float* __restrict__ depth, float* __restrict__ dnorm, int Bn)
{
    __shared__ float ls[8];
    __shared__ float smean, sstd;
    const int t = threadIdx.x, lane = t & 63, wv = t >> 6;
    float d = (t < Bn) ? depth[t] : 0.f;
    float s = d;
#pragma unroll
    for (int o = 32; o; o >>= 1) s += __shfl_down(s, o, 64);
    if (lane == 0) ls[wv] = s;
    __syncthreads();
    if (t == 0) {
        float tot = 0.f;
        for (int i = 0; i < 8; ++i) tot += ls[i];
        smean = tot / (float)Bn;
    }
    __syncthreads();
    float mean = smean;
    float df = (t < Bn) ? (d - mean) : 0.f;
    s = df * df;
#pragma unroll
    for (int o = 32; o; o >>= 1) s += __shfl_down(s, o, 64);
    __syncthreads();
    if (lane == 0) ls[wv] = s;
    __syncthreads();
    if (t == 0) {
        float tot = 0.f;
        for (int i = 0; i < 8; ++i) tot += ls[i];
        sstd = sqrtf(tot / (float)Bn);
    }
    __syncthreads();
    if (t < Bn) dnorm[t] = df / (sstd + 1e-6f);
}

// one wave per graph: z=[state_emb, goal_emb, dnorm]; pred = relu(z@W1+b1)@W2+b2
__global__ __launch_bounds__(256) void regress_kernel(
    const float* __restrict__ pool, const float* __restrict__ gcnt_s,
    const float* __restrict__ gcnt_g, const float* __restrict__ dnorm,
    const float* __restrict__ rW1, const float* __restrict__ rB1,
    const float* __restrict__ rW2, const float* __restrict__ rB2,
    float* __restrict__ pred, int Bn)
{
    const int lane = threadIdx.x & 63;
    const int g = (blockIdx.x * 256 + threadIdx.x) >> 6;
    if (g >= Bn) return;
    const float is = 1.f / fmaxf(gcnt_s[g], 1.f);
    const float ig = 1.f / fmaxf(gcnt_g[g], 1.f);
    const float* pr = pool + (size_t)g * 128;
    float acc = rB1[lane];
    for (int k = 0; k < 64; ++k)
        acc = fmaf(pr[k] * is, rW1[k * 64 + lane], acc);
    for (int k = 64; k < 128; ++k)
        acc = fmaf(pr[k] * ig, rW1[k * 64 + lane], acc);
    acc = fmaf(dnorm[g], rW1[128 * 64 + lane], acc);
    float v = fmaxf(acc, 0.f) * rW2[lane];
#pragma unroll
    for (int o = 32; o; o >>= 1) v += __shfl_down(v, o, 64);
    if (lane == 0) pred[g] = v + rB2[0];
}

// ---------------- launch ----------------

extern "C" void kernel_launch(void* const* d_in, const int* in_sizes, int n_in,
                              void* d_out, int out_size, void* d_ws, size_t ws_size,
                              hipStream_t stream)
{
    const int N = in_sizes[0] / 128;
    const int E = in_sizes[2];
    const int Bn = in_sizes[8];

    const float* state_x = (const float*)d_in[0];
    const int* s_ei = (const int*)d_in[1];
    const int* s_et = (const int*)d_in[2];
    const int* s_batch = (const int*)d_in[3];
    const float* goal_x = (const float*)d_in[4];
    const int* g_ei = (const int*)d_in[5];
    const int* g_et = (const int*)d_in[6];
    const int* g_batch = (const int*)d_in[7];
    const float* depth = (const float*)d_in[8];
    const float* sW1 = (const float*)d_in[9];
    const float* sRoot1 = (const float*)d_in[10];
    const float* sB1 = (const float*)d_in[11];
    const float* sW2 = (const float*)d_in[12];
    const float* sRoot2 = (const float*)d_in[13];
    const float* sB2 = (const float*)d_in[14];
    const float* gW1 = (const float*)d_in[15];
    const float* gRoot1 = (const float*)d_in[16];
    const float* gB1 = (const float*)d_in[17];
    const float* gW2 = (const float*)d_in[18];
    const float* gRoot2 = (const float*)d_in[19];
    const float* gB2 = (const float*)d_in[20];
    const float* rW1 = (const float*)d_in[21];
    const float* rB1 = (const float*)d_in[22];
    const float* rW2 = (const float*)d_in[23];
    const float* rB2 = (const float*)d_in[24];
    float* pred = (float*)d_out;

    const int EP_CAP = E + RNUM * EPB;

    char* p = (char*)d_ws;
    auto alloc = [&](size_t bytes) { char* r = p; p += WS_ALIGN(bytes); return r; };
    float* cnt    = (float*)alloc((size_t)N * RNUM * 4);   // int counts -> float inv
    int* hist     = (int*)alloc(RNUM * 4);
    int* poff     = (int*)alloc((RNUM + 1) * 4);
    int* cursor   = (int*)alloc(RNUM * 4);
    int* src_s    = (int*)alloc((size_t)EP_CAP * 4);
    int* dst_s    = (int*)alloc((size_t)EP_CAP * 4);
    float* h1     = (float*)alloc((size_t)N * HD * 4);
    float* h2     = (float*)alloc((size_t)N * HD * 4);
    float* pool   = (float*)alloc((size_t)Bn * 128 * 4);
    float* gcnt_s = (float*)alloc((size_t)Bn * 4);
    float* gcnt_g = (float*)alloc((size_t)Bn * 4);
    float* dnorm  = (float*)alloc((size_t)Bn * 4);

    hipMemsetAsync(pool, 0, (size_t)Bn * 128 * 4, stream);
    hipMemsetAsync(gcnt_s, 0, (size_t)Bn * 4, stream);
    hipMemsetAsync(gcnt_g, 0, (size_t)Bn * 4, stream);

    const int ebl = (E + 255) / 256;
    const int echunks = (EP_CAP + EPB - 1) / EPB;

    for (int enc = 0; enc < 2; ++enc) {
        const float* x = enc ? goal_x : state_x;
        const int* ei = enc ? g_ei : s_ei;
        const int* et = enc ? g_et : s_et;
        const int* batch = enc ? g_batch : s_batch;
        const float* W1 = enc ? gW1 : sW1;
        const float* Root1 = enc ? gRoot1 : sRoot1;
        const float* B1 = enc ? gB1 : sB1;
        const float* W2 = enc ? gW2 : sW2;
        const float* Root2 = enc ? gRoot2 : sRoot2;
        const float* B2 = enc ? gB2 : sB2;
        float* gcnt = enc ? gcnt_g : gcnt_s;

        const int* srcp = ei;
        const int* dstp = ei + E;

        hipMemsetAsync(cnt, 0, (size_t)N * RNUM * 4, stream);
        hipMemsetAsync(hist, 0, RNUM * 4, stream);
        hipMemsetAsync(cursor, 0, RNUM * 4, stream);

        count_kernel<<<ebl, 256, 0, stream>>>(dstp, et, (int*)cnt, hist, E);
        scan_kernel<<<1, 64, 0, stream>>>(hist, poff);
        invert_kernel<<<(N * RNUM + 255) / 256, 256, 0, stream>>>((int*)cnt, N * RNUM);
        scatter_kernel<<<ebl, 256, 0, stream>>>(srcp, dstp, et, poff, cursor, src_s, dst_s, E);

        // layer 1
        root_kernel<128><<<(N + 127) / 128, 256, 0, stream>>>(x, Root1, B1, h1, N);
        edge_kernel<128><<<echunks, 256, 0, stream>>>(x, src_s, dst_s, cnt, poff, hist, W1, h1);
        relu_kernel<<<(N * HD / 4 + 255) / 256, 256, 0, stream>>>(h1, N * HD / 4);
        // layer 2
        root_kernel<64><<<(N + 127) / 128, 256, 0, stream>>>(h1, Root2, B2, h2, N);
        edge_kernel<64><<<echunks, 256, 0, stream>>>(h1, src_s, dst_s, cnt, poff, hist, W2, h2);
        // pool (relu fused on read)
        int pwaves = (N + 255) / 256;
        pool_kernel<<<(pwaves * 64 + 255) / 256, 256, 0, stream>>>(h2, batch, pool, gcnt, enc * 64, N);
    }

    depth_kernel<<<1, 512, 0, stream>>>(depth, dnorm, Bn);
    regress_kernel<<<(Bn * 64 + 255) / 256, 256, 0, stream>>>(
        pool, gcnt_s, gcnt_g, dnorm, rW1, rB1, rW2, rB2, pred, Bn);
}

// Round 3
// 2310.674 us; speedup vs baseline: 2.6235x; 2.6235x over previous
//
#include <hip/hip_runtime.h>

// N=100000 nodes, E=1600000 edges, IN=128, H=64, R=32, B=512
constexpr int HD   = 64;
constexpr int RNUM = 32;
constexpr int EPB  = 256;   // rows per GEMM block (single-(chunk,type) via padding)
constexpr int MAXC = 32;    // max dst-chunks

typedef __attribute__((ext_vector_type(4))) float f32x4;
typedef __attribute__((ext_vector_type(8))) short bf16x8;

#define WS_ALIGN(x) (((x) + size_t(255)) & ~size_t(255))

__device__ inline float b2f(unsigned short u) {
    return __uint_as_float(((unsigned)u) << 16);
}
__device__ inline unsigned short f2b(float f) {
    unsigned u = __float_as_uint(f);
    u = (u + 0x7FFF + ((u >> 16) & 1)) >> 16;
    return (unsigned short)u;
}
__device__ inline unsigned pack2bf(float a, float b) {
    return (unsigned)f2b(a) | ((unsigned)f2b(b) << 16);
}

// ---------------- preprocessing ----------------

// per-edge: cnt[(dst,type)]++, deg[dst]++, hist[(chunk,type)]++
__global__ __launch_bounds__(256) void count_kernel(
    const int* __restrict__ dst, const int* __restrict__ et,
    int* __restrict__ cnt, int* __restrict__ deg, int* __restrict__ hist,
    int E, int shift)
{
    __shared__ int lh[MAXC * RNUM];
    for (int i = threadIdx.x; i < MAXC * RNUM; i += 256) lh[i] = 0;
    __syncthreads();
    int e = blockIdx.x * 256 + threadIdx.x;
    if (e < E) {
        int t = et[e];
        int d = dst[e];
        atomicAdd(&cnt[(size_t)d * RNUM + t], 1);
        atomicAdd(&deg[d], 1);
        atomicAdd(&lh[((d >> shift) << 5) + t], 1);
    }
    __syncthreads();
    for (int i = threadIdx.x; i < MAXC * RNUM; i += 256)
        if (lh[i] > 0) atomicAdd(&hist[i], lh[i]);
}

// per-chunk padded exclusive scan over 33 segments (32 relations + root)
__global__ void scan_chunks_kernel(const int* __restrict__ hist, int* __restrict__ poff,
                                   int N, int shift, int nc)
{
    if (threadIdx.x == 0) {
        int acc = 0;
        for (int c = 0; c < nc; ++c) {
            for (int r = 0; r < RNUM; ++r) {
                poff[c * 34 + r] = acc;
                acc += ((hist[c * RNUM + r] + EPB - 1) / EPB) * EPB;
            }
            poff[c * 34 + RNUM] = acc;
            int nlo = c << shift;
            int rn = N - nlo;
            int npc = 1 << shift;
            if (rn > npc) rn = npc;
            acc += ((rn + EPB - 1) / EPB) * EPB;
            poff[c * 34 + 33] = acc;
        }
    }
}

// generic exclusive scan (3 passes), elements get +addone
__global__ __launch_bounds__(256) void scan1_kernel(
    const int* __restrict__ in, int* __restrict__ out, int* __restrict__ part,
    int n, int addone)
{
    __shared__ int ls[256];
    const int base = blockIdx.x * 1024;
    const int i0 = base + threadIdx.x * 4;
    int v[4];
    int tot = 0;
#pragma unroll
    for (int u = 0; u < 4; ++u) {
        int x = (i0 + u < n) ? in[i0 + u] + addone : 0;
        v[u] = tot;
        tot += x;
    }
    ls[threadIdx.x] = tot;
    __syncthreads();
    for (int off = 1; off < 256; off <<= 1) {
        int x = (threadIdx.x >= off) ? ls[threadIdx.x - off] : 0;
        __syncthreads();
        ls[threadIdx.x] += x;
        __syncthreads();
    }
    int texcl = ls[threadIdx.x] - tot;
#pragma unroll
    for (int u = 0; u < 4; ++u)
        if (i0 + u < n) out[i0 + u] = texcl + v[u];
    if (threadIdx.x == 255) part[blockIdx.x] = ls[255];
}

__global__ void scan2_kernel(int* __restrict__ part, int nb, int* __restrict__ out, int n)
{
    if (threadIdx.x == 0) {
        int acc = 0;
        for (int i = 0; i < nb; ++i) { int t = part[i]; part[i] = acc; acc += t; }
        out[n] = acc;
    }
}

__global__ __launch_bounds__(256) void scan3_kernel(
    int* __restrict__ out, const int* __restrict__ part, int n)
{
    int i = blockIdx.x * 256 + threadIdx.x;
    if (i < n) out[i] += part[blockIdx.x >> 2];
}

// cnt(int) -> 1/max(cnt,1) (float) in place
__global__ __launch_bounds__(256) void invert_kernel(int* __restrict__ cnt, int total)
{
    int i = blockIdx.x * 256 + threadIdx.x;
    if (i < total) {
        int c = cnt[i];
        ((float*)cnt)[i] = 1.0f / (float)(c > 1 ? c : 1);
    }
}

// root pseudo-edges: segment 32 of node's chunk, identity, scale 1
__global__ __launch_bounds__(256) void root_fill_kernel(
    const int* __restrict__ poff, const int* __restrict__ nstart,
    int* __restrict__ ncur, int* __restrict__ c2src, float* __restrict__ scale_tm,
    int* __restrict__ e2c, int n, int shift)
{
    int d = blockIdx.x * 256 + threadIdx.x;
    if (d >= n) return;
    int c = d >> shift;
    int tm = poff[c * 34 + RNUM] + (d - (c << shift));
    c2src[tm] = d;
    scale_tm[tm] = 1.0f;
    e2c[nstart[d]] = tm;
    ncur[d] = 1;
}

// scatter edges into (chunk,type)-major slots + dst-major (dm) index
__global__ __launch_bounds__(256) void scatter_kernel(
    const int* __restrict__ src, const int* __restrict__ dst, const int* __restrict__ et,
    const int* __restrict__ poff, const float* __restrict__ inv,
    const int* __restrict__ nstart, int* __restrict__ ncur, int* __restrict__ tcur,
    int* __restrict__ c2src, float* __restrict__ scale_tm, int* __restrict__ e2c,
    int E, int shift)
{
    __shared__ int lh[MAXC * RNUM], lbase[MAXC * RNUM];
    for (int i = threadIdx.x; i < MAXC * RNUM; i += 256) lh[i] = 0;
    __syncthreads();
    int e = blockIdx.x * 256 + threadIdx.x;
    int t = 0, d = 0, s = 0, rank = 0, key = 0;
    bool valid = (e < E);
    if (valid) {
        t = et[e]; d = dst[e]; s = src[e];
        key = ((d >> shift) << 5) + t;
        rank = atomicAdd(&lh[key], 1);
    }
    __syncthreads();
    for (int i = threadIdx.x; i < MAXC * RNUM; i += 256)
        if (lh[i] > 0) lbase[i] = atomicAdd(&tcur[i], lh[i]);
    __syncthreads();
    if (valid) {
        int c = key >> 5;
        int tm = poff[c * 34 + t] + lbase[key] + rank;
        c2src[tm] = s;
        scale_tm[tm] = inv[(size_t)d * RNUM + t];
        int dm = nstart[d] + atomicAdd(&ncur[d], 1);
        e2c[dm] = tm;
    }
}

// f32 -> bf16 convert (8 elems/thread)
__global__ __launch_bounds__(256) void tobf16_kernel(
    const float* __restrict__ in, unsigned short* __restrict__ out, int total8)
{
    int i = blockIdx.x * 256 + threadIdx.x;
    if (i >= total8) return;
    const float4* ip = (const float4*)(in + (size_t)i * 8);
    float4 a = ip[0], b = ip[1];
    uint4 o;
    o.x = pack2bf(a.x, a.y); o.y = pack2bf(a.z, a.w);
    o.z = pack2bf(b.x, b.y); o.w = pack2bf(b.z, b.w);
    *(uint4*)(out + (size_t)i * 8) = o;
}

// pre-permute W (+Wroot as t=32) into MFMA A-fragment layout, bf16:
// wfrag[t][ks][jt][lane][8] = W[t][ks*32+(lane>>4)*8+jj][jt*16+(lane&15)]
template<int K>
__global__ __launch_bounds__(256) void wfrag_kernel(
    const float* __restrict__ W, const float* __restrict__ Root,
    unsigned short* __restrict__ wfrag)
{
    constexpr int KS = K / 32;
    int idx = blockIdx.x * 256 + threadIdx.x;
    int total = 33 * KS * 4 * 64;
    if (idx >= total) return;
    int lane = idx & 63;
    int tmp = idx >> 6;
    int jt = tmp & 3; tmp >>= 2;
    int ks = tmp % KS;
    int t = tmp / KS;
    int col = jt * 16 + (lane & 15);
    int kb = ks * 32 + (lane >> 4) * 8;
    const float* Wp = (t < RNUM) ? (W + ((size_t)t * K + kb) * HD + col)
                                 : (Root + (size_t)kb * HD + col);
    uint4 o;
    o.x = pack2bf(Wp[0 * HD], Wp[1 * HD]);
    o.y = pack2bf(Wp[2 * HD], Wp[3 * HD]);
    o.z = pack2bf(Wp[4 * HD], Wp[5 * HD]);
    o.w = pack2bf(Wp[6 * HD], Wp[7 * HD]);
    *(uint4*)(wfrag + (size_t)idx * 8) = o;
}

// type-grouped gather-GEMM for one chunk:
// C[row-base][j] = scale[row] * sum_k x[src[row]][k] * W[t][k][j]
template<int K>
__global__ __launch_bounds__(256) void gemm_kernel(
    const unsigned short* __restrict__ xb, const int* __restrict__ c2src,
    const float* __restrict__ scale_tm, const int* __restrict__ poff,
    const int* __restrict__ hist, const unsigned short* __restrict__ wfrag,
    unsigned short* __restrict__ C, int chunk, int shift, int N)
{
    constexpr int KS = K / 32;
    __shared__ unsigned short sW[KS * 4 * 64 * 8];
    const int* pc = poff + chunk * 34;
    const int base = pc[0];
    const int row0 = base + blockIdx.x * EPB;
    if (row0 >= pc[33]) return;
    int t = 0;
#pragma unroll
    for (int r = 1; r <= 33; ++r) t += (row0 >= pc[r]) ? 1 : 0;
    if (t >= 33) return;
    int vend;
    if (t < RNUM) {
        vend = pc[t] + hist[chunk * RNUM + t];
    } else {
        int nlo = chunk << shift;
        int rn = N - nlo;
        int npc = 1 << shift;
        if (rn > npc) rn = npc;
        vend = pc[RNUM] + rn;
    }
    if (row0 >= vend) return;
    {
        const uint4* wsrc = (const uint4*)(wfrag + (size_t)t * (KS * 2048));
        uint4* sd = (uint4*)sW;
        for (int i = threadIdx.x; i < KS * 256; i += 256) sd[i] = wsrc[i];
    }
    __syncthreads();
    const int lane = threadIdx.x & 63;
    const int erow0 = row0 + (threadIdx.x >> 6) * 64;
    int srcs[4], eg[4];
#pragma unroll
    for (int et = 0; et < 4; ++et) {
        eg[et] = erow0 + et * 16 + (lane & 15);
        int s = c2src[eg[et]];
        srcs[et] = s < 0 ? 0 : s;
    }
    const int ko = (lane >> 4) * 8;
    f32x4 acc[4][4];
#pragma unroll
    for (int a = 0; a < 4; ++a)
#pragma unroll
        for (int b = 0; b < 4; ++b) acc[a][b] = (f32x4)0.0f;

    for (int ks = 0; ks < KS; ++ks) {
        bf16x8 bx[4], aw[4];
#pragma unroll
        for (int et = 0; et < 4; ++et)
            bx[et] = *(const bf16x8*)(xb + (size_t)srcs[et] * K + ks * 32 + ko);
#pragma unroll
        for (int jt = 0; jt < 4; ++jt)
            aw[jt] = ((const bf16x8*)sW)[(ks * 4 + jt) * 64 + lane];
#pragma unroll
        for (int et = 0; et < 4; ++et)
#pragma unroll
            for (int jt = 0; jt < 4; ++jt)
                acc[et][jt] = __builtin_amdgcn_mfma_f32_16x16x32_bf16(
                    aw[jt], bx[et], acc[et][jt], 0, 0, 0);
    }
#pragma unroll
    for (int et = 0; et < 4; ++et) {
        float s = scale_tm[eg[et]];
        unsigned short* cr = C + (size_t)(eg[et] - base) * HD + (lane >> 4) * 4;
#pragma unroll
        for (int jt = 0; jt < 4; ++jt) {
            uint2 pk;
            pk.x = pack2bf(acc[et][jt][0] * s, acc[et][jt][1] * s);
            pk.y = pack2bf(acc[et][jt][2] * s, acc[et][jt][3] * s);
            *(uint2*)(cr + jt * 16) = pk;
        }
    }
}

// per-node CSR reduce for one chunk: h[node] = relu(bias + sum_e C[e2c[e]-base])
__global__ __launch_bounds__(256) void reduce_kernel(
    const unsigned short* __restrict__ C, const int* __restrict__ e2c,
    const int* __restrict__ nstart, const float* __restrict__ bias,
    unsigned short* __restrict__ hout, const int* __restrict__ poff,
    int chunk, int nlo, int nhi, int capr)
{
    int node = nlo + ((blockIdx.x * 256 + threadIdx.x) >> 6);
    int lane = threadIdx.x & 63;
    if (node >= nhi) return;
    const int base = poff[chunk * 34];
    int rs = nstart[node], re = nstart[node + 1];
    float acc = bias[lane];
    for (int e = rs; e < re; ++e) {
        int row = e2c[e] - base;
        if ((unsigned)row < (unsigned)capr)
            acc += b2f(C[(size_t)row * HD + lane]);
    }
    acc = fmaxf(acc, 0.f);
    hout[(size_t)node * HD + lane] = f2b(acc);
}

// mean-pool h per graph; batch sorted -> register run accumulation
__global__ __launch_bounds__(256) void pool_kernel(
    const unsigned short* __restrict__ h, const int* __restrict__ batch,
    float* __restrict__ pool, float* __restrict__ gcnt, int col0, int n)
{
    const int lane = threadIdx.x & 63;
    const int wid = (blockIdx.x * 256 + threadIdx.x) >> 6;
    const int RANGE = 256;
    int n0 = wid * RANGE;
    if (n0 >= n) return;
    int n1 = n0 + RANGE;
    if (n1 > n) n1 = n;
    int cur = batch[n0];
    float acc = 0.f, c = 0.f;
    for (int i = n0; i < n1; ++i) {
        int b = batch[i];
        if (b != cur) {
            unsafeAtomicAdd(&pool[(size_t)cur * 128 + col0 + lane], acc);
            if (lane == 0) unsafeAtomicAdd(&gcnt[cur], c);
            acc = 0.f; c = 0.f; cur = b;
        }
        acc += b2f(h[(size_t)i * HD + lane]);
        c += 1.f;
    }
    unsafeAtomicAdd(&pool[(size_t)cur * 128 + col0 + lane], acc);
    if (lane == 0) unsafeAtomicAdd(&gcnt[cur], c);
}

__global__ __launch_bounds__(512) void depth_kernel(
    const float* __restrict__ depth, float* __restrict__ dnorm, int Bn)
{
    __shared__ float ls[8];
    __shared__ float smean, sstd;
    const int t = threadIdx.x, lane = t & 63, wv = t >> 6;
    float d = (t < Bn) ? depth[t] : 0.f;
    float s = d;
#pragma unroll
    for (int o = 32; o; o >>= 1) s += __shfl_down(s, o, 64);
    if (lane == 0) ls[wv] = s;
    __syncthreads();
    if (t == 0) {
        float tot = 0.f;
        for (int i = 0; i < 8; ++i) tot += ls[i];
        smean = tot / (float)Bn;
    }
    __syncthreads();
    float mean = smean;
    float df = (t < Bn) ? (d - mean) : 0.f;
    s = df * df;
#pragma unroll
    for (int o = 32; o; o >>= 1) s += __shfl_down(s, o, 64);
    __syncthreads();
    if (lane == 0) ls[wv] = s;
    __syncthreads();
    if (t == 0) {
        float tot = 0.f;
        for (int i = 0; i < 8; ++i) tot += ls[i];
        sstd = sqrtf(tot / (float)Bn);
    }
    __syncthreads();
    if (t < Bn) dnorm[t] = df / (sstd + 1e-6f);
}

__global__ __launch_bounds__(256) void regress_kernel(
    const float* __restrict__ pool, const float* __restrict__ gcnt_s,
    const float* __restrict__ gcnt_g, const float* __restrict__ dnorm,
    const float* __restrict__ rW1, const float* __restrict__ rB1,
    const float* __restrict__ rW2, const float* __restrict__ rB2,
    float* __restrict__ pred, int Bn)
{
    const int lane = threadIdx.x & 63;
    const int g = (blockIdx.x * 256 + threadIdx.x) >> 6;
    if (g >= Bn) return;
    const float is = 1.f / fmaxf(gcnt_s[g], 1.f);
    const float ig = 1.f / fmaxf(gcnt_g[g], 1.f);
    const float* pr = pool + (size_t)g * 128;
    float acc = rB1[lane];
    for (int k = 0; k < 64; ++k)
        acc = fmaf(pr[k] * is, rW1[k * 64 + lane], acc);
    for (int k = 64; k < 128; ++k)
        acc = fmaf(pr[k] * ig, rW1[k * 64 + lane], acc);
    acc = fmaf(dnorm[g], rW1[128 * 64 + lane], acc);
    float v = fmaxf(acc, 0.f) * rW2[lane];
#pragma unroll
    for (int o = 32; o; o >>= 1) v += __shfl_down(v, o, 64);
    if (lane == 0) pred[g] = v + rB2[0];
}

// ---------------- launch ----------------

extern "C" void kernel_launch(void* const* d_in, const int* in_sizes, int n_in,
                              void* d_out, int out_size, void* d_ws, size_t ws_size,
                              hipStream_t stream)
{
    const int E1 = in_sizes[2];
    const int E2 = in_sizes[6];
    const int Emax = E1 > E2 ? E1 : E2;
    const int N = in_sizes[3];
    const int IN = in_sizes[0] / N;   // 128
    const int Bn = in_sizes[8];

    const float* state_x = (const float*)d_in[0];
    const int* s_ei = (const int*)d_in[1];
    const int* s_et = (const int*)d_in[2];
    const int* s_batch = (const int*)d_in[3];
    const float* goal_x = (const float*)d_in[4];
    const int* g_ei = (const int*)d_in[5];
    const int* g_et = (const int*)d_in[6];
    const int* g_batch = (const int*)d_in[7];
    const float* depth = (const float*)d_in[8];
    const float* sW1 = (const float*)d_in[9];
    const float* sRoot1 = (const float*)d_in[10];
    const float* sB1 = (const float*)d_in[11];
    const float* sW2 = (const float*)d_in[12];
    const float* sRoot2 = (const float*)d_in[13];
    const float* sB2 = (const float*)d_in[14];
    const float* gW1 = (const float*)d_in[15];
    const float* gRoot1 = (const float*)d_in[16];
    const float* gB1 = (const float*)d_in[17];
    const float* gW2 = (const float*)d_in[18];
    const float* gRoot2 = (const float*)d_in[19];
    const float* gB2 = (const float*)d_in[20];
    const float* rW1 = (const float*)d_in[21];
    const float* rB1 = (const float*)d_in[22];
    const float* rW2 = (const float*)d_in[23];
    const float* rB2 = (const float*)d_in[24];
    float* pred = (float*)d_out;

    const int nbScan = (N + 1023) / 1024;

    // ---- choose chunking so workspace fits ws_size ----
    int shift = 0, nc = 1;
    size_t RT = 0, CAPR = 0;
    {
        const int targets[6] = {1, 2, 4, 8, 16, 32};
        for (int ti = 0; ti < 6; ++ti) {
            int target = targets[ti];
            int npc_t = (N + target - 1) / target;
            int sh = 0;
            while ((1 << sh) < npc_t) sh++;
            int npc = 1 << sh;
            int ncn = (N + npc - 1) / npc;
            size_t rt = WS_ALIGN(((size_t)Emax + N + (size_t)ncn * 33 * EPB) * 1) ;
            rt = (((size_t)Emax + N + (size_t)ncn * 33 * EPB) + 255) / 256 * 256;
            size_t capr;
            if (ncn == 1) capr = rt;
            else {
                double per = (double)(Emax + N) * npc / N * 1.25 + 33.0 * EPB;
                capr = ((size_t)per + 255) / 256 * 256;
                if (capr > rt) capr = rt;
            }
            size_t fixedb = 0;
            fixedb += WS_ALIGN((size_t)N * 4);          // deg
            fixedb += WS_ALIGN((size_t)(N + 1) * 4);    // nstart
            fixedb += WS_ALIGN((size_t)N * 4);          // ncur
            fixedb += WS_ALIGN((size_t)nbScan * 4);     // part
            fixedb += WS_ALIGN((size_t)ncn * RNUM * 4); // hist
            fixedb += WS_ALIGN((size_t)ncn * 34 * 4);   // poff
            fixedb += WS_ALIGN((size_t)ncn * RNUM * 4); // tcur
            fixedb += WS_ALIGN(rt * 4);                 // c2src
            fixedb += WS_ALIGN(rt * 4);                 // scale_tm
            fixedb += WS_ALIGN(((size_t)Emax + N) * 4); // e2c
            fixedb += WS_ALIGN((size_t)N * IN * 2);     // xb
            fixedb += WS_ALIGN((size_t)N * HD * 2);     // h1
            fixedb += WS_ALIGN((size_t)N * HD * 2);     // h2
            fixedb += WS_ALIGN((size_t)33 * 4 * 4 * 64 * 8 * 2); // wf1
            fixedb += WS_ALIGN((size_t)33 * 2 * 4 * 64 * 8 * 2); // wf2
            fixedb += WS_ALIGN((size_t)Bn * 128 * 4);   // pool
            fixedb += 3 * WS_ALIGN((size_t)Bn * 4);     // gcnt_s, gcnt_g, dnorm
            size_t unib = WS_ALIGN((size_t)N * RNUM * 4);
            size_t cb = WS_ALIGN(capr * (size_t)HD * 2);
            if (cb > unib) unib = cb;
            size_t total = fixedb + unib + (size_t)(8 << 20);
            if (total <= ws_size || ti == 5) {
                shift = sh; nc = ncn; RT = rt; CAPR = capr;
                break;
            }
        }
    }
    const int npc = 1 << shift;

    char* p = (char*)d_ws;
    auto alloc = [&](size_t bytes) { char* r = p; p += WS_ALIGN(bytes); return r; };
    int* deg        = (int*)alloc((size_t)N * 4);
    int* nstart     = (int*)alloc((size_t)(N + 1) * 4);
    int* ncur       = (int*)alloc((size_t)N * 4);
    int* part       = (int*)alloc((size_t)nbScan * 4);
    int* hist       = (int*)alloc((size_t)nc * RNUM * 4);
    int* poff       = (int*)alloc((size_t)nc * 34 * 4);
    int* tcur       = (int*)alloc((size_t)nc * RNUM * 4);
    int* c2src      = (int*)alloc(RT * 4);
    float* scale_tm = (float*)alloc(RT * 4);
    int* e2c        = (int*)alloc(((size_t)Emax + N) * 4);
    unsigned short* xb  = (unsigned short*)alloc((size_t)N * IN * 2);
    unsigned short* h1  = (unsigned short*)alloc((size_t)N * HD * 2);
    unsigned short* h2  = (unsigned short*)alloc((size_t)N * HD * 2);
    unsigned short* wf1 = (unsigned short*)alloc((size_t)33 * 4 * 4 * 64 * 8 * 2);
    unsigned short* wf2 = (unsigned short*)alloc((size_t)33 * 2 * 4 * 64 * 8 * 2);
    float* pool     = (float*)alloc((size_t)Bn * 128 * 4);
    float* gcnt_s   = (float*)alloc((size_t)Bn * 4);
    float* gcnt_g   = (float*)alloc((size_t)Bn * 4);
    float* dnorm    = (float*)alloc((size_t)Bn * 4);
    // union region: cnt (count/scatter phase) and C (gemm/reduce phase)
    char* uni = p;
    float* cnt        = (float*)uni;                 // N*RNUM*4
    unsigned short* C = (unsigned short*)uni;        // CAPR*HD*2

    hipMemsetAsync(pool, 0, (size_t)Bn * 128 * 4, stream);
    hipMemsetAsync(gcnt_s, 0, (size_t)Bn * 4, stream);
    hipMemsetAsync(gcnt_g, 0, (size_t)Bn * 4, stream);

    const int gemmBlocks = (int)(CAPR / EPB);

    for (int enc = 0; enc < 2; ++enc) {
        const float* x = enc ? goal_x : state_x;
        const int* ei = enc ? g_ei : s_ei;
        const int* et = enc ? g_et : s_et;
        const int* batch = enc ? g_batch : s_batch;
        const float* W1 = enc ? gW1 : sW1;
        const float* Root1 = enc ? gRoot1 : sRoot1;
        const float* B1 = enc ? gB1 : sB1;
        const float* W2 = enc ? gW2 : sW2;
        const float* Root2 = enc ? gRoot2 : sRoot2;
        const float* B2 = enc ? gB2 : sB2;
        float* gcnt = enc ? gcnt_g : gcnt_s;
        const int E = enc ? E2 : E1;
        const int* srcp = ei;
        const int* dstp = ei + E;
        const int ebl = (E + 255) / 256;

        hipMemsetAsync(cnt, 0, (size_t)N * RNUM * 4, stream);
        hipMemsetAsync(deg, 0, (size_t)N * 4, stream);
        hipMemsetAsync(hist, 0, (size_t)nc * RNUM * 4, stream);
        hipMemsetAsync(tcur, 0, (size_t)nc * RNUM * 4, stream);
        hipMemsetAsync(c2src, 0xFF, RT * 4, stream);

        count_kernel<<<ebl, 256, 0, stream>>>(dstp, et, (int*)cnt, deg, hist, E, shift);
        scan_chunks_kernel<<<1, 64, 0, stream>>>(hist, poff, N, shift, nc);
        scan1_kernel<<<nbScan, 256, 0, stream>>>(deg, nstart, part, N, 1);
        scan2_kernel<<<1, 64, 0, stream>>>(part, nbScan, nstart, N);
        scan3_kernel<<<nbScan * 4, 256, 0, stream>>>(nstart, part, N);
        invert_kernel<<<(N * RNUM + 255) / 256, 256, 0, stream>>>((int*)cnt, N * RNUM);
        root_fill_kernel<<<(N + 255) / 256, 256, 0, stream>>>(
            poff, nstart, ncur, c2src, scale_tm, e2c, N, shift);
        scatter_kernel<<<ebl, 256, 0, stream>>>(
            srcp, dstp, et, poff, cnt, nstart, ncur, tcur, c2src, scale_tm, e2c, E, shift);

        tobf16_kernel<<<(N * IN / 8 + 255) / 256, 256, 0, stream>>>(x, xb, N * IN / 8);
        wfrag_kernel<128><<<(33 * 4 * 4 * 64 + 255) / 256, 256, 0, stream>>>(W1, Root1, wf1);
        wfrag_kernel<64><<<(33 * 2 * 4 * 64 + 255) / 256, 256, 0, stream>>>(W2, Root2, wf2);

        // layer 1
        for (int c = 0; c < nc; ++c) {
            int nlo = c << shift;
            int nhi = nlo + npc; if (nhi > N) nhi = N;
            gemm_kernel<128><<<gemmBlocks, 256, 0, stream>>>(
                xb, c2src, scale_tm, poff, hist, wf1, C, c, shift, N);
            reduce_kernel<<<((nhi - nlo) + 3) / 4, 256, 0, stream>>>(
                C, e2c, nstart, B1, h1, poff, c, nlo, nhi, (int)CAPR);
        }
        // layer 2
        for (int c = 0; c < nc; ++c) {
            int nlo = c << shift;
            int nhi = nlo + npc; if (nhi > N) nhi = N;
            gemm_kernel<64><<<gemmBlocks, 256, 0, stream>>>(
                h1, c2src, scale_tm, poff, hist, wf2, C, c, shift, N);
            reduce_kernel<<<((nhi - nlo) + 3) / 4, 256, 0, stream>>>(
                C, e2c, nstart, B2, h2, poff, c, nlo, nhi, (int)CAPR);
        }
        // pool
        int pwaves = (N + 255) / 256;
        pool_kernel<<<(pwaves * 64 + 255) / 256, 256, 0, stream>>>(
            h2, batch, pool, gcnt, enc * 64, N);
    }

    depth_kernel<<<1, 512, 0, stream>>>(depth, dnorm, Bn);
    regress_kernel<<<(Bn * 64 + 255) / 256, 256, 0, stream>>>(
        pool, gcnt_s, gcnt_g, dnorm, rW1, rB1, rW2, rB2, pred, Bn);
}

// Round 4
// 2159.557 us; speedup vs baseline: 2.8071x; 1.0700x over previous
//
#include <hip/hip_runtime.h>

// N=100000 nodes, E=1600000 edges, IN=128, H=64, R=32, B=512
constexpr int HD   = 64;
constexpr int RNUM = 32;
constexpr int EPB  = 256;   // rows per GEMM block (single-(chunk,type) via padding)
constexpr int MAXC = 32;    // max dst-chunks

typedef __attribute__((ext_vector_type(4))) float f32x4;
typedef __attribute__((ext_vector_type(8))) short bf16x8;

#define WS_ALIGN(x) (((x) + size_t(255)) & ~size_t(255))

__device__ inline float b2f(unsigned short u) {
    return __uint_as_float(((unsigned)u) << 16);
}
__device__ inline unsigned short f2b(float f) {
    unsigned u = __float_as_uint(f);
    u = (u + 0x7FFF + ((u >> 16) & 1)) >> 16;
    return (unsigned short)u;
}
__device__ inline unsigned pack2bf(float a, float b) {
    return (unsigned)f2b(a) | ((unsigned)f2b(b) << 16);
}

// ---------------- preprocessing ----------------

// per-edge: deg[dst]++ (dense, cheap), hist[(chunk,type)]++ (LDS-aggregated)
__global__ __launch_bounds__(256) void count_kernel(
    const int* __restrict__ dst, const int* __restrict__ et,
    int* __restrict__ deg, int* __restrict__ hist, int E, int shift)
{
    __shared__ int lh[MAXC * RNUM];
    for (int i = threadIdx.x; i < MAXC * RNUM; i += 256) lh[i] = 0;
    __syncthreads();
    int e = blockIdx.x * 256 + threadIdx.x;
    if (e < E) {
        int t = et[e];
        int d = dst[e];
        atomicAdd(&deg[d], 1);
        atomicAdd(&lh[((d >> shift) << 5) + t], 1);
    }
    __syncthreads();
    for (int i = threadIdx.x; i < MAXC * RNUM; i += 256)
        if (lh[i] > 0) atomicAdd(&hist[i], lh[i]);
}

// per-chunk padded exclusive scan over 33 segments (32 relations + root)
__global__ void scan_chunks_kernel(const int* __restrict__ hist, int* __restrict__ poff,
                                   int N, int shift, int nc)
{
    if (threadIdx.x == 0) {
        int acc = 0;
        for (int c = 0; c < nc; ++c) {
            for (int r = 0; r < RNUM; ++r) {
                poff[c * 34 + r] = acc;
                acc += ((hist[c * RNUM + r] + EPB - 1) / EPB) * EPB;
            }
            poff[c * 34 + RNUM] = acc;
            int nlo = c << shift;
            int rn = N - nlo;
            int npc = 1 << shift;
            if (rn > npc) rn = npc;
            acc += ((rn + EPB - 1) / EPB) * EPB;
            poff[c * 34 + 33] = acc;
        }
    }
}

// generic exclusive scan (3 passes), elements get +addone
__global__ __launch_bounds__(256) void scan1_kernel(
    const int* __restrict__ in, int* __restrict__ out, int* __restrict__ part,
    int n, int addone)
{
    __shared__ int ls[256];
    const int base = blockIdx.x * 1024;
    const int i0 = base + threadIdx.x * 4;
    int v[4];
    int tot = 0;
#pragma unroll
    for (int u = 0; u < 4; ++u) {
        int x = (i0 + u < n) ? in[i0 + u] + addone : 0;
        v[u] = tot;
        tot += x;
    }
    ls[threadIdx.x] = tot;
    __syncthreads();
    for (int off = 1; off < 256; off <<= 1) {
        int x = (threadIdx.x >= off) ? ls[threadIdx.x - off] : 0;
        __syncthreads();
        ls[threadIdx.x] += x;
        __syncthreads();
    }
    int texcl = ls[threadIdx.x] - tot;
#pragma unroll
    for (int u = 0; u < 4; ++u)
        if (i0 + u < n) out[i0 + u] = texcl + v[u];
    if (threadIdx.x == 255) part[blockIdx.x] = ls[255];
}

__global__ void scan2_kernel(int* __restrict__ part, int nb, int* __restrict__ out, int n)
{
    if (threadIdx.x == 0) {
        int acc = 0;
        for (int i = 0; i < nb; ++i) { int t = part[i]; part[i] = acc; acc += t; }
        out[n] = acc;
    }
}

__global__ __launch_bounds__(256) void scan3_kernel(
    int* __restrict__ out, const int* __restrict__ part, int n)
{
    int i = blockIdx.x * 256 + threadIdx.x;
    if (i < n) out[i] += part[blockIdx.x >> 2];
}

// root pseudo-edges: segment 32 of node's chunk, identity
__global__ __launch_bounds__(256) void root_fill_kernel(
    const int* __restrict__ poff, const int* __restrict__ nstart,
    int* __restrict__ ncur, int* __restrict__ c2src, int* __restrict__ e2c,
    int n, int shift)
{
    int d = blockIdx.x * 256 + threadIdx.x;
    if (d >= n) return;
    int c = d >> shift;
    int tm = poff[c * 34 + RNUM] + (d - (c << shift));
    c2src[tm] = d;
    e2c[nstart[d]] = tm | (RNUM << 24);
    ncur[d] = 1;
}

// scatter edges into (chunk,type)-major slots + dst-major (dm) index (type packed)
__global__ __launch_bounds__(256) void scatter_kernel(
    const int* __restrict__ src, const int* __restrict__ dst, const int* __restrict__ et,
    const int* __restrict__ poff,
    const int* __restrict__ nstart, int* __restrict__ ncur, int* __restrict__ tcur,
    int* __restrict__ c2src, int* __restrict__ e2c, int E, int shift)
{
    __shared__ int lh[MAXC * RNUM], lbase[MAXC * RNUM];
    for (int i = threadIdx.x; i < MAXC * RNUM; i += 256) lh[i] = 0;
    __syncthreads();
    int e = blockIdx.x * 256 + threadIdx.x;
    int t = 0, d = 0, s = 0, rank = 0, key = 0;
    bool valid = (e < E);
    if (valid) {
        t = et[e]; d = dst[e]; s = src[e];
        key = ((d >> shift) << 5) + t;
        rank = atomicAdd(&lh[key], 1);
    }
    __syncthreads();
    for (int i = threadIdx.x; i < MAXC * RNUM; i += 256)
        if (lh[i] > 0) lbase[i] = atomicAdd(&tcur[i], lh[i]);
    __syncthreads();
    if (valid) {
        int c = key >> 5;
        int tm = poff[c * 34 + t] + lbase[key] + rank;
        c2src[tm] = s;
        int dm = nstart[d] + atomicAdd(&ncur[d], 1);
        e2c[dm] = tm | (t << 24);
    }
}

// f32 -> bf16 convert (8 elems/thread)
__global__ __launch_bounds__(256) void tobf16_kernel(
    const float* __restrict__ in, unsigned short* __restrict__ out, int total8)
{
    int i = blockIdx.x * 256 + threadIdx.x;
    if (i >= total8) return;
    const float4* ip = (const float4*)(in + (size_t)i * 8);
    float4 a = ip[0], b = ip[1];
    uint4 o;
    o.x = pack2bf(a.x, a.y); o.y = pack2bf(a.z, a.w);
    o.z = pack2bf(b.x, b.y); o.w = pack2bf(b.z, b.w);
    *(uint4*)(out + (size_t)i * 8) = o;
}

// pre-permute W (+Wroot as t=32) into MFMA A-fragment layout, bf16
template<int K>
__global__ __launch_bounds__(256) void wfrag_kernel(
    const float* __restrict__ W, const float* __restrict__ Root,
    unsigned short* __restrict__ wfrag)
{
    constexpr int KS = K / 32;
    int idx = blockIdx.x * 256 + threadIdx.x;
    int total = 33 * KS * 4 * 64;
    if (idx >= total) return;
    int lane = idx & 63;
    int tmp = idx >> 6;
    int jt = tmp & 3; tmp >>= 2;
    int ks = tmp % KS;
    int t = tmp / KS;
    int col = jt * 16 + (lane & 15);
    int kb = ks * 32 + (lane >> 4) * 8;
    const float* Wp = (t < RNUM) ? (W + ((size_t)t * K + kb) * HD + col)
                                 : (Root + (size_t)kb * HD + col);
    uint4 o;
    o.x = pack2bf(Wp[0 * HD], Wp[1 * HD]);
    o.y = pack2bf(Wp[2 * HD], Wp[3 * HD]);
    o.z = pack2bf(Wp[4 * HD], Wp[5 * HD]);
    o.w = pack2bf(Wp[6 * HD], Wp[7 * HD]);
    *(uint4*)(wfrag + (size_t)idx * 8) = o;
}

// type-grouped gather-GEMM for one chunk (unscaled messages):
// C[row-base][j] = sum_k x[src[row]][k] * W[t][k][j]
template<int K>
__global__ __launch_bounds__(256) void gemm_kernel(
    const unsigned short* __restrict__ xb, const int* __restrict__ c2src,
    const int* __restrict__ poff, const int* __restrict__ hist,
    const unsigned short* __restrict__ wfrag, unsigned short* __restrict__ C,
    int chunk, int shift, int N)
{
    constexpr int KS = K / 32;
    __shared__ unsigned short sW[KS * 4 * 64 * 8];
    const int* pc = poff + chunk * 34;
    const int base = pc[0];
    const int row0 = base + blockIdx.x * EPB;
    if (row0 >= pc[33]) return;
    int t = 0;
#pragma unroll
    for (int r = 1; r <= 33; ++r) t += (row0 >= pc[r]) ? 1 : 0;
    if (t >= 33) return;
    int vend;
    if (t < RNUM) {
        vend = pc[t] + hist[chunk * RNUM + t];
    } else {
        int nlo = chunk << shift;
        int rn = N - nlo;
        int npc = 1 << shift;
        if (rn > npc) rn = npc;
        vend = pc[RNUM] + rn;
    }
    if (row0 >= vend) return;
    {
        const uint4* wsrc = (const uint4*)(wfrag + (size_t)t * (KS * 2048));
        uint4* sd = (uint4*)sW;
        for (int i = threadIdx.x; i < KS * 256; i += 256) sd[i] = wsrc[i];
    }
    __syncthreads();
    const int lane = threadIdx.x & 63;
    const int erow0 = row0 + (threadIdx.x >> 6) * 64;
    int srcs[4], eg[4];
#pragma unroll
    for (int et = 0; et < 4; ++et) {
        eg[et] = erow0 + et * 16 + (lane & 15);
        srcs[et] = (eg[et] < vend) ? c2src[eg[et]] : 0;  // padding -> safe src 0
    }
    const int ko = (lane >> 4) * 8;
    f32x4 acc[4][4];
#pragma unroll
    for (int a = 0; a < 4; ++a)
#pragma unroll
        for (int b = 0; b < 4; ++b) acc[a][b] = (f32x4)0.0f;

    for (int ks = 0; ks < KS; ++ks) {
        bf16x8 bx[4], aw[4];
#pragma unroll
        for (int et = 0; et < 4; ++et)
            bx[et] = *(const bf16x8*)(xb + (size_t)srcs[et] * K + ks * 32 + ko);
#pragma unroll
        for (int jt = 0; jt < 4; ++jt)
            aw[jt] = ((const bf16x8*)sW)[(ks * 4 + jt) * 64 + lane];
#pragma unroll
        for (int et = 0; et < 4; ++et)
#pragma unroll
            for (int jt = 0; jt < 4; ++jt)
                acc[et][jt] = __builtin_amdgcn_mfma_f32_16x16x32_bf16(
                    aw[jt], bx[et], acc[et][jt], 0, 0, 0);
    }
#pragma unroll
    for (int et = 0; et < 4; ++et) {
        unsigned short* cr = C + (size_t)(eg[et] - base) * HD + (lane >> 4) * 4;
#pragma unroll
        for (int jt = 0; jt < 4; ++jt) {
            uint2 pk;
            pk.x = pack2bf(acc[et][jt][0], acc[et][jt][1]);
            pk.y = pack2bf(acc[et][jt][2], acc[et][jt][3]);
            *(uint2*)(cr + jt * 16) = pk;
        }
    }
}

// per-node CSR reduce with on-the-fly per-type mean:
// h[node] = relu(bias + sum_t (1/cnt_t) sum_{e of type t} C[row_e])
__global__ __launch_bounds__(256) void reduce_kernel(
    const unsigned short* __restrict__ C, const int* __restrict__ e2c,
    const int* __restrict__ nstart, const float* __restrict__ bias,
    unsigned short* __restrict__ hout, const int* __restrict__ poff,
    int chunk, int nlo, int nhi, int capr)
{
    __shared__ int cnts[4][36];
    __shared__ float invs[4][36];
    const int wid = threadIdx.x >> 6;
    const int lane = threadIdx.x & 63;
    const int node = nlo + ((blockIdx.x * 256 + threadIdx.x) >> 6);
    const bool active = node < nhi;
    int rs = 0, re = 0;
    if (active) { rs = nstart[node]; re = nstart[node + 1]; }
    if (lane < 34) cnts[wid][lane] = 0;
    __syncthreads();
    for (int e = rs + lane; e < re; e += 64) {
        int t = (e2c[e] >> 24) & 63;
        atomicAdd(&cnts[wid][t], 1);
    }
    __syncthreads();
    if (lane < 34) {
        int c = cnts[wid][lane];
        invs[wid][lane] = 1.0f / (float)(c > 1 ? c : 1);
    }
    __syncthreads();
    const int base = poff[chunk * 34];
    float acc = bias[lane];
    if (active) {
        for (int e = rs; e < re; ++e) {
            int pk = e2c[e];
            int row = (pk & 0xFFFFFF) - base;
            float iv = invs[wid][(pk >> 24) & 63];
            if ((unsigned)row < (unsigned)capr)
                acc += iv * b2f(C[(size_t)row * HD + lane]);
        }
        acc = fmaxf(acc, 0.f);
        hout[(size_t)node * HD + lane] = f2b(acc);
    }
}

// mean-pool h per graph; batch sorted -> register run accumulation
__global__ __launch_bounds__(256) void pool_kernel(
    const unsigned short* __restrict__ h, const int* __restrict__ batch,
    float* __restrict__ pool, float* __restrict__ gcnt, int col0, int n)
{
    const int lane = threadIdx.x & 63;
    const int wid = (blockIdx.x * 256 + threadIdx.x) >> 6;
    const int RANGE = 256;
    int n0 = wid * RANGE;
    if (n0 >= n) return;
    int n1 = n0 + RANGE;
    if (n1 > n) n1 = n;
    int cur = batch[n0];
    float acc = 0.f, c = 0.f;
    for (int i = n0; i < n1; ++i) {
        int b = batch[i];
        if (b != cur) {
            unsafeAtomicAdd(&pool[(size_t)cur * 128 + col0 + lane], acc);
            if (lane == 0) unsafeAtomicAdd(&gcnt[cur], c);
            acc = 0.f; c = 0.f; cur = b;
        }
        acc += b2f(h[(size_t)i * HD + lane]);
        c += 1.f;
    }
    unsafeAtomicAdd(&pool[(size_t)cur * 128 + col0 + lane], acc);
    if (lane == 0) unsafeAtomicAdd(&gcnt[cur], c);
}

__global__ __launch_bounds__(512) void depth_kernel(
    const float* __restrict__ depth, float* __restrict__ dnorm, int Bn)
{
    __shared__ float ls[8];
    __shared__ float smean, sstd;
    const int t = threadIdx.x, lane = t & 63, wv = t >> 6;
    float d = (t < Bn) ? depth[t] : 0.f;
    float s = d;
#pragma unroll
    for (int o = 32; o; o >>= 1) s += __shfl_down(s, o, 64);
    if (lane == 0) ls[wv] = s;
    __syncthreads();
    if (t == 0) {
        float tot = 0.f;
        for (int i = 0; i < 8; ++i) tot += ls[i];
        smean = tot / (float)Bn;
    }
    __syncthreads();
    float mean = smean;
    float df = (t < Bn) ? (d - mean) : 0.f;
    s = df * df;
#pragma unroll
    for (int o = 32; o; o >>= 1) s += __shfl_down(s, o, 64);
    __syncthreads();
    if (lane == 0) ls[wv] = s;
    __syncthreads();
    if (t == 0) {
        float tot = 0.f;
        for (int i = 0; i < 8; ++i) tot += ls[i];
        sstd = sqrtf(tot / (float)Bn);
    }
    __syncthreads();
    if (t < Bn) dnorm[t] = df / (sstd + 1e-6f);
}

__global__ __launch_bounds__(256) void regress_kernel(
    const float* __restrict__ pool, const float* __restrict__ gcnt_s,
    const float* __restrict__ gcnt_g, const float* __restrict__ dnorm,
    const float* __restrict__ rW1, const float* __restrict__ rB1,
    const float* __restrict__ rW2, const float* __restrict__ rB2,
    float* __restrict__ pred, int Bn)
{
    const int lane = threadIdx.x & 63;
    const int g = (blockIdx.x * 256 + threadIdx.x) >> 6;
    if (g >= Bn) return;
    const float is = 1.f / fmaxf(gcnt_s[g], 1.f);
    const float ig = 1.f / fmaxf(gcnt_g[g], 1.f);
    const float* pr = pool + (size_t)g * 128;
    float acc = rB1[lane];
    for (int k = 0; k < 64; ++k)
        acc = fmaf(pr[k] * is, rW1[k * 64 + lane], acc);
    for (int k = 64; k < 128; ++k)
        acc = fmaf(pr[k] * ig, rW1[k * 64 + lane], acc);
    acc = fmaf(dnorm[g], rW1[128 * 64 + lane], acc);
    float v = fmaxf(acc, 0.f) * rW2[lane];
#pragma unroll
    for (int o = 32; o; o >>= 1) v += __shfl_down(v, o, 64);
    if (lane == 0) pred[g] = v + rB2[0];
}

// ---------------- launch ----------------

extern "C" void kernel_launch(void* const* d_in, const int* in_sizes, int n_in,
                              void* d_out, int out_size, void* d_ws, size_t ws_size,
                              hipStream_t stream)
{
    const int E1 = in_sizes[2];
    const int E2 = in_sizes[6];
    const int Emax = E1 > E2 ? E1 : E2;
    const int N = in_sizes[3];
    const int IN = in_sizes[0] / N;   // 128
    const int Bn = in_sizes[8];

    const float* state_x = (const float*)d_in[0];
    const int* s_ei = (const int*)d_in[1];
    const int* s_et = (const int*)d_in[2];
    const int* s_batch = (const int*)d_in[3];
    const float* goal_x = (const float*)d_in[4];
    const int* g_ei = (const int*)d_in[5];
    const int* g_et = (const int*)d_in[6];
    const int* g_batch = (const int*)d_in[7];
    const float* depth = (const float*)d_in[8];
    const float* sW1 = (const float*)d_in[9];
    const float* sRoot1 = (const float*)d_in[10];
    const float* sB1 = (const float*)d_in[11];
    const float* sW2 = (const float*)d_in[12];
    const float* sRoot2 = (const float*)d_in[13];
    const float* sB2 = (const float*)d_in[14];
    const float* gW1 = (const float*)d_in[15];
    const float* gRoot1 = (const float*)d_in[16];
    const float* gB1 = (const float*)d_in[17];
    const float* gW2 = (const float*)d_in[18];
    const float* gRoot2 = (const float*)d_in[19];
    const float* gB2 = (const float*)d_in[20];
    const float* rW1 = (const float*)d_in[21];
    const float* rB1 = (const float*)d_in[22];
    const float* rW2 = (const float*)d_in[23];
    const float* rB2 = (const float*)d_in[24];
    float* pred = (float*)d_out;

    const int nbScan = (N + 1023) / 1024;

    // ---- choose chunking so workspace fits ws_size ----
    int shift = 0, nc = 1;
    size_t RT = 0, CAPR = 0;
    {
        const int targets[6] = {1, 2, 4, 8, 16, 32};
        for (int ti = 0; ti < 6; ++ti) {
            int target = targets[ti];
            int npc_t = (N + target - 1) / target;
            int sh = 0;
            while ((1 << sh) < npc_t) sh++;
            int npc = 1 << sh;
            int ncn = (N + npc - 1) / npc;
            size_t rt = (((size_t)Emax + N + (size_t)ncn * 33 * EPB) + 255) / 256 * 256;
            size_t capr;
            if (ncn == 1) capr = rt;
            else {
                double per = (double)(Emax + N) * npc / N * 1.25 + 33.0 * EPB;
                capr = ((size_t)per + 255) / 256 * 256;
                if (capr > rt) capr = rt;
            }
            size_t fixedb = 0;
            fixedb += WS_ALIGN((size_t)N * 4);          // deg
            fixedb += WS_ALIGN((size_t)(N + 1) * 4);    // nstart
            fixedb += WS_ALIGN((size_t)N * 4);          // ncur
            fixedb += WS_ALIGN((size_t)nbScan * 4);     // part
            fixedb += WS_ALIGN((size_t)ncn * RNUM * 4); // hist
            fixedb += WS_ALIGN((size_t)ncn * 34 * 4);   // poff
            fixedb += WS_ALIGN((size_t)ncn * RNUM * 4); // tcur
            fixedb += WS_ALIGN(rt * 4);                 // c2src
            fixedb += WS_ALIGN(((size_t)Emax + N) * 4); // e2c
            fixedb += WS_ALIGN((size_t)N * IN * 2);     // xb
            fixedb += WS_ALIGN((size_t)N * HD * 2);     // h1
            fixedb += WS_ALIGN((size_t)N * HD * 2);     // h2
            fixedb += WS_ALIGN((size_t)33 * 4 * 4 * 64 * 8 * 2); // wf1
            fixedb += WS_ALIGN((size_t)33 * 2 * 4 * 64 * 8 * 2); // wf2
            fixedb += WS_ALIGN((size_t)Bn * 128 * 4);   // pool
            fixedb += 3 * WS_ALIGN((size_t)Bn * 4);     // gcnt_s, gcnt_g, dnorm
            size_t cb = WS_ALIGN(capr * (size_t)HD * 2);
            size_t total = fixedb + cb + (size_t)(8 << 20);
            if (total <= ws_size || ti == 5) {
                shift = sh; nc = ncn; RT = rt; CAPR = capr;
                break;
            }
        }
    }
    const int npc = 1 << shift;

    char* p = (char*)d_ws;
    auto alloc = [&](size_t bytes) { char* r = p; p += WS_ALIGN(bytes); return r; };
    int* deg        = (int*)alloc((size_t)N * 4);
    int* nstart     = (int*)alloc((size_t)(N + 1) * 4);
    int* ncur       = (int*)alloc((size_t)N * 4);
    int* part       = (int*)alloc((size_t)nbScan * 4);
    int* hist       = (int*)alloc((size_t)nc * RNUM * 4);
    int* poff       = (int*)alloc((size_t)nc * 34 * 4);
    int* tcur       = (int*)alloc((size_t)nc * RNUM * 4);
    int* c2src      = (int*)alloc(RT * 4);
    int* e2c        = (int*)alloc(((size_t)Emax + N) * 4);
    unsigned short* xb  = (unsigned short*)alloc((size_t)N * IN * 2);
    unsigned short* h1  = (unsigned short*)alloc((size_t)N * HD * 2);
    unsigned short* h2  = (unsigned short*)alloc((size_t)N * HD * 2);
    unsigned short* wf1 = (unsigned short*)alloc((size_t)33 * 4 * 4 * 64 * 8 * 2);
    unsigned short* wf2 = (unsigned short*)alloc((size_t)33 * 2 * 4 * 64 * 8 * 2);
    float* pool     = (float*)alloc((size_t)Bn * 128 * 4);
    float* gcnt_s   = (float*)alloc((size_t)Bn * 4);
    float* gcnt_g   = (float*)alloc((size_t)Bn * 4);
    float* dnorm    = (float*)alloc((size_t)Bn * 4);
    unsigned short* C = (unsigned short*)alloc(CAPR * (size_t)HD * 2);

    hipMemsetAsync(pool, 0, (size_t)Bn * 128 * 4, stream);
    hipMemsetAsync(gcnt_s, 0, (size_t)Bn * 4, stream);
    hipMemsetAsync(gcnt_g, 0, (size_t)Bn * 4, stream);

    const int gemmBlocks = (int)(CAPR / EPB);

    for (int enc = 0; enc < 2; ++enc) {
        const float* x = enc ? goal_x : state_x;
        const int* ei = enc ? g_ei : s_ei;
        const int* et = enc ? g_et : s_et;
        const int* batch = enc ? g_batch : s_batch;
        const float* W1 = enc ? gW1 : sW1;
        const float* Root1 = enc ? gRoot1 : sRoot1;
        const float* B1 = enc ? gB1 : sB1;
        const float* W2 = enc ? gW2 : sW2;
        const float* Root2 = enc ? gRoot2 : sRoot2;
        const float* B2 = enc ? gB2 : sB2;
        float* gcnt = enc ? gcnt_g : gcnt_s;
        const int E = enc ? E2 : E1;
        const int* srcp = ei;
        const int* dstp = ei + E;
        const int ebl = (E + 255) / 256;

        hipMemsetAsync(deg, 0, (size_t)N * 4, stream);
        hipMemsetAsync(hist, 0, (size_t)nc * RNUM * 4, stream);
        hipMemsetAsync(tcur, 0, (size_t)nc * RNUM * 4, stream);

        count_kernel<<<ebl, 256, 0, stream>>>(dstp, et, deg, hist, E, shift);
        scan_chunks_kernel<<<1, 64, 0, stream>>>(hist, poff, N, shift, nc);
        scan1_kernel<<<nbScan, 256, 0, stream>>>(deg, nstart, part, N, 1);
        scan2_kernel<<<1, 64, 0, stream>>>(part, nbScan, nstart, N);
        scan3_kernel<<<nbScan * 4, 256, 0, stream>>>(nstart, part, N);
        root_fill_kernel<<<(N + 255) / 256, 256, 0, stream>>>(
            poff, nstart, ncur, c2src, e2c, N, shift);
        scatter_kernel<<<ebl, 256, 0, stream>>>(
            srcp, dstp, et, poff, nstart, ncur, tcur, c2src, e2c, E, shift);

        tobf16_kernel<<<(N * IN / 8 + 255) / 256, 256, 0, stream>>>(x, xb, N * IN / 8);
        wfrag_kernel<128><<<(33 * 4 * 4 * 64 + 255) / 256, 256, 0, stream>>>(W1, Root1, wf1);
        wfrag_kernel<64><<<(33 * 2 * 4 * 64 + 255) / 256, 256, 0, stream>>>(W2, Root2, wf2);

        // layer 1
        for (int c = 0; c < nc; ++c) {
            int nlo = c << shift;
            int nhi = nlo + npc; if (nhi > N) nhi = N;
            gemm_kernel<128><<<gemmBlocks, 256, 0, stream>>>(
                xb, c2src, poff, hist, wf1, C, c, shift, N);
            reduce_kernel<<<((nhi - nlo) + 3) / 4, 256, 0, stream>>>(
                C, e2c, nstart, B1, h1, poff, c, nlo, nhi, (int)CAPR);
        }
        // layer 2
        for (int c = 0; c < nc; ++c) {
            int nlo = c << shift;
            int nhi = nlo + npc; if (nhi > N) nhi = N;
            gemm_kernel<64><<<gemmBlocks, 256, 0, stream>>>(
                h1, c2src, poff, hist, wf2, C, c, shift, N);
            reduce_kernel<<<((nhi - nlo) + 3) / 4, 256, 0, stream>>>(
                C, e2c, nstart, B2, h2, poff, c, nlo, nhi, (int)CAPR);
        }
        // pool
        int pwaves = (N + 255) / 256;
        pool_kernel<<<(pwaves * 64 + 255) / 256, 256, 0, stream>>>(
            h2, batch, pool, gcnt, enc * 64, N);
    }

    depth_kernel<<<1, 512, 0, stream>>>(depth, dnorm, Bn);
    regress_kernel<<<(Bn * 64 + 255) / 256, 256, 0, stream>>>(
        pool, gcnt_s, gcnt_g, dnorm, rW1, rB1, rW2, rB2, pred, Bn);
}